// Round 1
// baseline (995.485 us; speedup 1.0000x reference)
//
#include <hip/hip_runtime.h>

#define N_NODES 100000
#define N_EDGES 1600000
#define N_SUP 2
#define IN_DIM 256
#define OUT_DIM 64

// ---------------------------------------------------------------------------
// GEMM: pre_sup[i] = x @ W[i] for i=0,1 in one pass over x.
// Block = 256 threads (4 waves). Block handles 16 rows; each wave 4 rows,
// lane = output column (64 cols). x tile staged in LDS (16x256 f32 = 16 KB),
// read back with wave-uniform address (LDS broadcast, conflict-free).
// W column loads are coalesced (lane i -> consecutive floats) and L1/L2-hot
// (W is only 128 KB total).
// ---------------------------------------------------------------------------
__global__ __launch_bounds__(256) void gemm_kernel(
    const float* __restrict__ x, const float* __restrict__ W,
    float* __restrict__ ps)  // ps: [N_SUP][N_NODES][OUT_DIM]
{
    __shared__ float xs[16][IN_DIM];
    const int row0 = blockIdx.x * 16;

    // cooperative load: 16*256 floats = 1024 float4, 256 threads x 4 each
    const float4* xv = (const float4*)(x + (size_t)row0 * IN_DIM);
    float4* xsv = (float4*)&xs[0][0];
#pragma unroll
    for (int i = 0; i < 4; ++i)
        xsv[threadIdx.x + 256 * i] = xv[threadIdx.x + 256 * i];
    __syncthreads();

    const int wave = threadIdx.x >> 6;
    const int lane = threadIdx.x & 63;
    const int r0 = wave * 4;

    float acc0[4] = {0.f, 0.f, 0.f, 0.f};
    float acc1[4] = {0.f, 0.f, 0.f, 0.f};
    const float* W0 = W + lane;                        // W[0][k][lane]
    const float* W1 = W + IN_DIM * OUT_DIM + lane;     // W[1][k][lane]

    for (int k = 0; k < IN_DIM; ++k) {
        float w0 = W0[k * OUT_DIM];
        float w1 = W1[k * OUT_DIM];
#pragma unroll
        for (int r = 0; r < 4; ++r) {
            float xr = xs[r0 + r][k];
            acc0[r] = fmaf(xr, w0, acc0[r]);
            acc1[r] = fmaf(xr, w1, acc1[r]);
        }
    }

    float* p0 = ps + (size_t)(row0 + r0) * OUT_DIM + lane;
    float* p1 = p0 + (size_t)N_NODES * OUT_DIM;
#pragma unroll
    for (int r = 0; r < 4; ++r) {
        p0[r * OUT_DIM] = acc0[r];
        p1[r * OUT_DIM] = acc1[r];
    }
}

// ---------------------------------------------------------------------------
// Zero-init d_out (harness poisons it with 0xAA before every launch).
// ---------------------------------------------------------------------------
__global__ __launch_bounds__(256) void zero_kernel(float4* __restrict__ out)
{
    out[blockIdx.x * 256 + threadIdx.x] = make_float4(0.f, 0.f, 0.f, 0.f);
}

// ---------------------------------------------------------------------------
// Scatter: one wave per edge. lane = channel. Gather pre_sup row (coalesced
// 256 B), scale by edge_val, hardware-fp32-atomic add into out[dst].
// atomicAdd on global is device-scope -> safe across XCDs.
// ---------------------------------------------------------------------------
__global__ __launch_bounds__(256) void scatter_kernel(
    const float* __restrict__ ps, const float* __restrict__ edge_val,
    const int* __restrict__ edge_src, const int* __restrict__ edge_dst,
    float* __restrict__ out)
{
    const int sup = blockIdx.y;
    const int e = blockIdx.x * 4 + (threadIdx.x >> 6);
    if (e >= N_EDGES) return;
    const int lane = threadIdx.x & 63;

    const size_t eoff = (size_t)sup * N_EDGES + e;
    const int src = edge_src[eoff];
    const int dst = edge_dst[eoff];
    const float val = edge_val[eoff];

    const float* psi = ps + (size_t)sup * N_NODES * OUT_DIM;
    float msg = psi[(size_t)src * OUT_DIM + lane] * val;
    unsafeAtomicAdd(&out[(size_t)dst * OUT_DIM + lane], msg);
}

// ---------------------------------------------------------------------------
// In-place ReLU on d_out.
// ---------------------------------------------------------------------------
__global__ __launch_bounds__(256) void relu_kernel(float4* __restrict__ out)
{
    const int i = blockIdx.x * 256 + threadIdx.x;
    float4 v = out[i];
    v.x = fmaxf(v.x, 0.f);
    v.y = fmaxf(v.y, 0.f);
    v.z = fmaxf(v.z, 0.f);
    v.w = fmaxf(v.w, 0.f);
    out[i] = v;
}

extern "C" void kernel_launch(void* const* d_in, const int* in_sizes, int n_in,
                              void* d_out, int out_size, void* d_ws, size_t ws_size,
                              hipStream_t stream)
{
    const float* x        = (const float*)d_in[0];  // [N_NODES, IN_DIM]
    const float* W        = (const float*)d_in[1];  // [N_SUP, IN_DIM, OUT_DIM]
    const float* edge_val = (const float*)d_in[2];  // [N_SUP, N_EDGES]
    const int*   edge_src = (const int*)d_in[3];    // [N_SUP, N_EDGES]
    const int*   edge_dst = (const int*)d_in[4];    // [N_SUP, N_EDGES]
    float* out = (float*)d_out;                     // [N_NODES, OUT_DIM]
    float* ps  = (float*)d_ws;                      // 2 * 100000 * 64 f32 = 51.2 MB

    // pre_sup for both supports in one pass over x
    gemm_kernel<<<N_NODES / 16, 256, 0, stream>>>(x, W, ps);

    // zero output accumulator (out_size = 6.4M floats = 1.6M float4)
    zero_kernel<<<(N_NODES * OUT_DIM) / 1024, 256, 0, stream>>>((float4*)out);

    // scatter-add both supports
    dim3 sgrid(N_EDGES / 4, N_SUP);
    scatter_kernel<<<sgrid, 256, 0, stream>>>(ps, edge_val, edge_src, edge_dst, out);

    // relu in place
    relu_kernel<<<(N_NODES * OUT_DIM) / 1024, 256, 0, stream>>>((float4*)out);
}

// Round 2
// 839.451 us; speedup vs baseline: 1.1859x; 1.1859x over previous
//
#include <hip/hip_runtime.h>

#define N_NODES 100000
#define N_EDGES 1600000
#define N_SUP 2
#define IN_DIM 256
#define OUT_DIM 64
#define N_TOT_EDGES (N_SUP * N_EDGES)   // 3,200,000
#define N1 (N_NODES + 1)                // 100,001 (scan length; last elem stays 0 -> start[N]=total)

// ---------------------------------------------------------------------------
// GEMM: pre_sup[i] = x @ W[i] for i=0,1 in one pass over x. (unchanged R1)
// ---------------------------------------------------------------------------
__global__ __launch_bounds__(256) void gemm_kernel(
    const float* __restrict__ x, const float* __restrict__ W,
    float* __restrict__ ps)  // ps: [N_SUP][N_NODES][OUT_DIM]
{
    __shared__ float xs[16][IN_DIM];
    const int row0 = blockIdx.x * 16;

    const float4* xv = (const float4*)(x + (size_t)row0 * IN_DIM);
    float4* xsv = (float4*)&xs[0][0];
#pragma unroll
    for (int i = 0; i < 4; ++i)
        xsv[threadIdx.x + 256 * i] = xv[threadIdx.x + 256 * i];
    __syncthreads();

    const int wave = threadIdx.x >> 6;
    const int lane = threadIdx.x & 63;
    const int r0 = wave * 4;

    float acc0[4] = {0.f, 0.f, 0.f, 0.f};
    float acc1[4] = {0.f, 0.f, 0.f, 0.f};
    const float* W0 = W + lane;
    const float* W1 = W + IN_DIM * OUT_DIM + lane;

    for (int k = 0; k < IN_DIM; ++k) {
        float w0 = W0[k * OUT_DIM];
        float w1 = W1[k * OUT_DIM];
#pragma unroll
        for (int r = 0; r < 4; ++r) {
            float xr = xs[r0 + r][k];
            acc0[r] = fmaf(xr, w0, acc0[r]);
            acc1[r] = fmaf(xr, w1, acc1[r]);
        }
    }

    float* p0 = ps + (size_t)(row0 + r0) * OUT_DIM + lane;
    float* p1 = p0 + (size_t)N_NODES * OUT_DIM;
#pragma unroll
    for (int r = 0; r < 4; ++r) {
        p0[r * OUT_DIM] = acc0[r];
        p1[r * OUT_DIM] = acc1[r];
    }
}

// ---------------------------------------------------------------------------
// CSR build, step 0: zero the degree histogram (ws is poisoned 0xAA).
// ---------------------------------------------------------------------------
__global__ __launch_bounds__(256) void zero_deg_kernel(int* __restrict__ deg)
{
    int i = blockIdx.x * 256 + threadIdx.x;
    if (i < N1) deg[i] = 0;
}

// step 1: histogram of dst over BOTH supports (out sums them anyway).
__global__ __launch_bounds__(256) void hist_kernel(
    const int* __restrict__ edge_dst, int* __restrict__ deg)
{
    int gid = blockIdx.x * 256 + threadIdx.x;   // < N_TOT_EDGES exactly
    atomicAdd(&deg[edge_dst[gid]], 1);
}

// step 2a: per-block (1024-elem) sums of deg -> bsum[98]
#define SCAN_NB ((N1 + 1023) / 1024)            // 98
__global__ __launch_bounds__(256) void scan1_kernel(
    const int* __restrict__ deg, int* __restrict__ bsum)
{
    __shared__ int sh[256];
    int base = blockIdx.x * 1024 + threadIdx.x * 4;
    int s = 0;
#pragma unroll
    for (int j = 0; j < 4; ++j) {
        int idx = base + j;
        if (idx < N1) s += deg[idx];
    }
    sh[threadIdx.x] = s;
    __syncthreads();
    for (int off = 128; off > 0; off >>= 1) {
        if (threadIdx.x < off) sh[threadIdx.x] += sh[threadIdx.x + off];
        __syncthreads();
    }
    if (threadIdx.x == 0) bsum[blockIdx.x] = sh[0];
}

// step 2b: serial exclusive scan of the 98 block sums (tiny).
__global__ void scan2_kernel(int* __restrict__ bsum)
{
    if (threadIdx.x == 0 && blockIdx.x == 0) {
        int acc = 0;
        for (int i = 0; i < SCAN_NB; ++i) {
            int v = bsum[i];
            bsum[i] = acc;
            acc += v;
        }
    }
}

// step 2c: per-block exclusive scan + block offset -> start[] and cursor[]
__global__ __launch_bounds__(256) void scan3_kernel(
    const int* __restrict__ deg, const int* __restrict__ bsum,
    int* __restrict__ start, int* __restrict__ cursor)
{
    __shared__ int sh[256];
    int base = blockIdx.x * 1024 + threadIdx.x * 4;
    int v[4];
    int tsum = 0;
#pragma unroll
    for (int j = 0; j < 4; ++j) {
        int idx = base + j;
        v[j] = (idx < N1) ? deg[idx] : 0;
        tsum += v[j];
    }
    sh[threadIdx.x] = tsum;
    __syncthreads();
    // Hillis-Steele inclusive scan over 256 thread sums
    for (int off = 1; off < 256; off <<= 1) {
        int add = (threadIdx.x >= off) ? sh[threadIdx.x - off] : 0;
        __syncthreads();
        sh[threadIdx.x] += add;
        __syncthreads();
    }
    int pre = sh[threadIdx.x] - tsum + bsum[blockIdx.x];  // exclusive prefix
#pragma unroll
    for (int j = 0; j < 4; ++j) {
        int idx = base + j;
        if (idx < N1) {
            start[idx] = pre;
            cursor[idx] = pre;
        }
        pre += v[j];
    }
}

// step 3: fill edge records grouped by dst. rec = (ps_row, val_bits).
__global__ __launch_bounds__(256) void fill_kernel(
    const int* __restrict__ edge_src, const int* __restrict__ edge_dst,
    const float* __restrict__ edge_val,
    int* __restrict__ cursor, int2* __restrict__ erec)
{
    int gid = blockIdx.x * 256 + threadIdx.x;   // < N_TOT_EDGES exactly
    int sup = (gid >= N_EDGES) ? 1 : 0;
    int src = edge_src[gid];
    int dst = edge_dst[gid];
    float val = edge_val[gid];
    int pos = atomicAdd(&cursor[dst], 1);
    erec[pos] = make_int2(sup * N_NODES + src, __float_as_int(val));
}

// ---------------------------------------------------------------------------
// Gather: one wave per node, lane = channel. Atomic-free; ReLU fused.
// Lanes cooperatively load <=64 edge recs (coalesced), broadcast via shfl,
// each edge contributes one coalesced 256 B ps-row read.
// ---------------------------------------------------------------------------
__global__ __launch_bounds__(256) void gather_kernel(
    const float* __restrict__ ps, const int* __restrict__ start,
    const int2* __restrict__ erec, float* __restrict__ out)
{
    const int n = blockIdx.x * 4 + (threadIdx.x >> 6);
    const int lane = threadIdx.x & 63;
    const int s = start[n];
    const int e = start[n + 1];

    float acc = 0.f;
    for (int base = s; base < e; base += 64) {
        const int cnt = min(64, e - base);
        int2 r = make_int2(0, 0);
        if (base + lane < e) r = erec[base + lane];
        for (int j = 0; j < cnt; ++j) {
            int  row = __shfl(r.x, j);
            float val = __int_as_float(__shfl(r.y, j));
            acc = fmaf(ps[(size_t)row * OUT_DIM + lane], val, acc);
        }
    }
    out[(size_t)n * OUT_DIM + lane] = fmaxf(acc, 0.f);
}

extern "C" void kernel_launch(void* const* d_in, const int* in_sizes, int n_in,
                              void* d_out, int out_size, void* d_ws, size_t ws_size,
                              hipStream_t stream)
{
    const float* x        = (const float*)d_in[0];  // [N_NODES, IN_DIM]
    const float* W        = (const float*)d_in[1];  // [N_SUP, IN_DIM, OUT_DIM]
    const float* edge_val = (const float*)d_in[2];  // [N_SUP, N_EDGES]
    const int*   edge_src = (const int*)d_in[3];    // [N_SUP, N_EDGES]
    const int*   edge_dst = (const int*)d_in[4];    // [N_SUP, N_EDGES]
    float* out = (float*)d_out;                     // [N_NODES, OUT_DIM]

    // workspace layout (all 16 B aligned):
    //   ps     [N_SUP*N_NODES*OUT_DIM f32]  = 51,200,000 B
    //   deg    [N1 int]                     @ 51,200,000  (400,016 B padded)
    //   start  [N1 int]                     @ 51,600,016
    //   cursor [N1 int]                     @ 52,000,032
    //   erec   [N_TOT_EDGES int2]           @ 52,400,048  (25,600,000 B)
    float* ps = (float*)d_ws;
    char* p = (char*)d_ws + 51200000;
    int* deg    = (int*)(p);
    int* start  = (int*)(p + 400016);
    int* cursor = (int*)(p + 800032);
    int2* erec  = (int2*)(p + 1200048);

    // pre_sup for both supports in one pass over x
    gemm_kernel<<<N_NODES / 16, 256, 0, stream>>>(x, W, ps);

    // CSR-by-dst build
    zero_deg_kernel<<<(N1 + 255) / 256, 256, 0, stream>>>(deg);
    hist_kernel<<<N_TOT_EDGES / 256, 256, 0, stream>>>(edge_dst, deg);
    scan1_kernel<<<SCAN_NB, 256, 0, stream>>>(deg, start /*reuse as bsum? no*/);
    // NOTE: bsum stored in 'cursor' temporarily is unsafe (scan3 writes it);
    // use the tail of deg? deg is still needed by scan3. Use a small dedicated
    // region just past erec instead:
    // (re-launch with correct bsum pointer below)
    // -- the line above already ran with 'start' as bsum; fix by using a real
    //    bsum buffer and re-running scan1 correctly:
    {
        int* bsum = (int*)((char*)erec + (size_t)N_TOT_EDGES * sizeof(int2)); // 98 ints
        scan1_kernel<<<SCAN_NB, 256, 0, stream>>>(deg, bsum);
        scan2_kernel<<<1, 64, 0, stream>>>(bsum);
        scan3_kernel<<<SCAN_NB, 256, 0, stream>>>(deg, bsum, start, cursor);
    }
    fill_kernel<<<N_TOT_EDGES / 256, 256, 0, stream>>>(edge_src, edge_dst,
                                                       edge_val, cursor, erec);

    // atomic-free pull gather + fused ReLU (writes every out row; no zero pass)
    gather_kernel<<<N_NODES / 4, 256, 0, stream>>>(ps, start, erec, out);
}

// Round 3
// 651.161 us; speedup vs baseline: 1.5288x; 1.2892x over previous
//
#include <hip/hip_runtime.h>

#define N_NODES 100000
#define N_EDGES 1600000
#define N_SUP 2
#define IN_DIM 256
#define OUT_DIM 64
#define N_TOT_EDGES (N_SUP * N_EDGES)   // 3,200,000
#define N1 (N_NODES + 1)                // scan length
#define GM 64                           // GEMM M-tile per block
#define NBLK ((N_NODES + GM - 1) / GM)  // 1563

typedef __attribute__((ext_vector_type(8))) short short8;   // 8 bf16
typedef __attribute__((ext_vector_type(4))) float floatx4;  // MFMA acc

__device__ inline ushort f2bf(float f) {          // fp32 -> bf16 RNE
    unsigned u = __float_as_uint(f);
    return (ushort)((u + 0x7fffu + ((u >> 16) & 1u)) >> 16);
}
__device__ inline float bf2f(ushort h) {
    return __uint_as_float(((unsigned)h) << 16);
}

// ---------------------------------------------------------------------------
// W pre-swizzle: Wcat[k][n] (n<64 -> sup0, n>=64 -> sup1) laid out in
// B-fragment order for mfma_f32_16x16x32_bf16:
//   Wb[ks][nt][lane][j] = Wcat[ks*32 + (lane>>4)*8 + j][nt*16 + (lane&15)]
// so a wave's B-frag load is one coalesced 16 B dwordx4 per lane.
// ---------------------------------------------------------------------------
__global__ __launch_bounds__(256) void wb_kernel(
    const float* __restrict__ W, ushort* __restrict__ Wb)
{
    int idx = blockIdx.x * 256 + threadIdx.x;      // 0..32767
    int j    = idx & 7;
    int lane = (idx >> 3) & 63;
    int nt   = (idx >> 9) & 7;
    int ks   = idx >> 12;
    int k = ks * 32 + (lane >> 4) * 8 + j;
    int n = nt * 16 + (lane & 15);
    Wb[idx] = f2bf(W[((size_t)(n >> 6) * IN_DIM + k) * OUT_DIM + (n & 63)]);
}

// ---------------------------------------------------------------------------
// MFMA GEMM: psb[sup][node][64] (bf16) = x @ W[sup], both supports at once
// as C[100000 x 128]. Block: 256 thr = 4 waves, M-tile 64, full K=256 in LDS
// (bf16, rows padded to 264 -> 528 B = 33x16 B: b128-aligned, 2-way-max bank
// aliasing which is free). Wave w owns cols [32w, 32w+32): 4 m-tiles x 2
// n-tiles of 16x16x32 MFMA, acc 32 VGPRs.
// ---------------------------------------------------------------------------
__global__ __launch_bounds__(256) void gemm_kernel(
    const float* __restrict__ x, const ushort* __restrict__ Wb,
    ushort* __restrict__ psb)
{
    __shared__ __align__(16) ushort xs[GM][264];
    const int row0 = blockIdx.x * GM;
    const int trow = threadIdx.x >> 6;
    const int tcol = threadIdx.x & 63;

    // stage x tile -> bf16 LDS; clamp OOB rows (stores are guarded later)
#pragma unroll
    for (int j = 0; j < 16; ++j) {
        int r = j * 4 + trow;
        int gr = row0 + r;
        if (gr > N_NODES - 1) gr = N_NODES - 1;
        float4 v = ((const float4*)x)[(size_t)gr * 64 + tcol];
        ushort4 h;
        h.x = f2bf(v.x); h.y = f2bf(v.y); h.z = f2bf(v.z); h.w = f2bf(v.w);
        *(ushort4*)&xs[r][tcol * 4] = h;
    }
    __syncthreads();

    const int wave = threadIdx.x >> 6;
    const int lane = threadIdx.x & 63;
    const int q = lane >> 4;       // quad
    const int m = lane & 15;
    const int nt0 = wave * 2;      // first of this wave's two 16-col n-tiles

    floatx4 acc[4][2];
#pragma unroll
    for (int mt = 0; mt < 4; ++mt)
#pragma unroll
        for (int nt = 0; nt < 2; ++nt)
            acc[mt][nt] = (floatx4){0.f, 0.f, 0.f, 0.f};

    const short8* Wbv = (const short8*)Wb;
#pragma unroll
    for (int ks = 0; ks < 8; ++ks) {
        short8 b0 = Wbv[((ks * 8) + nt0) * 64 + lane];
        short8 b1 = Wbv[((ks * 8) + nt0 + 1) * 64 + lane];
#pragma unroll
        for (int mt = 0; mt < 4; ++mt) {
            short8 a = *(const short8*)&xs[mt * 16 + m][ks * 32 + q * 8];
            acc[mt][0] = __builtin_amdgcn_mfma_f32_16x16x32_bf16(a, b0, acc[mt][0], 0, 0, 0);
            acc[mt][1] = __builtin_amdgcn_mfma_f32_16x16x32_bf16(a, b1, acc[mt][1], 0, 0, 0);
        }
    }

    // C/D layout: col = lane&15, row = (lane>>4)*4 + reg  [m89-verified]
#pragma unroll
    for (int mt = 0; mt < 4; ++mt) {
#pragma unroll
        for (int nt = 0; nt < 2; ++nt) {
            int col = wave * 32 + nt * 16 + m;
            int sup = col >> 6, ch = col & 63;
#pragma unroll
            for (int r = 0; r < 4; ++r) {
                int row = row0 + mt * 16 + q * 4 + r;
                if (row < N_NODES)
                    psb[((size_t)sup * N_NODES + row) * OUT_DIM + ch] =
                        f2bf(acc[mt][nt][r]);
            }
        }
    }
}

// ---------------------------------------------------------------------------
// CSR-by-dst build (unchanged from R2, minus the stray duplicate scan)
// ---------------------------------------------------------------------------
__global__ __launch_bounds__(256) void zero_deg_kernel(int* __restrict__ deg)
{
    int i = blockIdx.x * 256 + threadIdx.x;
    if (i < N1) deg[i] = 0;
}

__global__ __launch_bounds__(256) void hist_kernel(
    const int* __restrict__ edge_dst, int* __restrict__ deg)
{
    int gid = blockIdx.x * 256 + threadIdx.x;
    atomicAdd(&deg[edge_dst[gid]], 1);
}

#define SCAN_NB ((N1 + 1023) / 1024)            // 98
__global__ __launch_bounds__(256) void scan1_kernel(
    const int* __restrict__ deg, int* __restrict__ bsum)
{
    __shared__ int sh[256];
    int base = blockIdx.x * 1024 + threadIdx.x * 4;
    int s = 0;
#pragma unroll
    for (int j = 0; j < 4; ++j) {
        int idx = base + j;
        if (idx < N1) s += deg[idx];
    }
    sh[threadIdx.x] = s;
    __syncthreads();
    for (int off = 128; off > 0; off >>= 1) {
        if (threadIdx.x < off) sh[threadIdx.x] += sh[threadIdx.x + off];
        __syncthreads();
    }
    if (threadIdx.x == 0) bsum[blockIdx.x] = sh[0];
}

__global__ void scan2_kernel(int* __restrict__ bsum)
{
    if (threadIdx.x == 0 && blockIdx.x == 0) {
        int acc = 0;
        for (int i = 0; i < SCAN_NB; ++i) {
            int v = bsum[i];
            bsum[i] = acc;
            acc += v;
        }
    }
}

__global__ __launch_bounds__(256) void scan3_kernel(
    const int* __restrict__ deg, const int* __restrict__ bsum,
    int* __restrict__ start, int* __restrict__ cursor)
{
    __shared__ int sh[256];
    int base = blockIdx.x * 1024 + threadIdx.x * 4;
    int v[4];
    int tsum = 0;
#pragma unroll
    for (int j = 0; j < 4; ++j) {
        int idx = base + j;
        v[j] = (idx < N1) ? deg[idx] : 0;
        tsum += v[j];
    }
    sh[threadIdx.x] = tsum;
    __syncthreads();
    for (int off = 1; off < 256; off <<= 1) {
        int add = (threadIdx.x >= off) ? sh[threadIdx.x - off] : 0;
        __syncthreads();
        sh[threadIdx.x] += add;
        __syncthreads();
    }
    int pre = sh[threadIdx.x] - tsum + bsum[blockIdx.x];
#pragma unroll
    for (int j = 0; j < 4; ++j) {
        int idx = base + j;
        if (idx < N1) {
            start[idx] = pre;
            cursor[idx] = pre;
        }
        pre += v[j];
    }
}

__global__ __launch_bounds__(256) void fill_kernel(
    const int* __restrict__ edge_src, const int* __restrict__ edge_dst,
    const float* __restrict__ edge_val,
    int* __restrict__ cursor, int2* __restrict__ erec)
{
    int gid = blockIdx.x * 256 + threadIdx.x;
    int sup = (gid >= N_EDGES) ? 1 : 0;
    int src = edge_src[gid];
    int dst = edge_dst[gid];
    float val = edge_val[gid];
    int pos = atomicAdd(&cursor[dst], 1);
    erec[pos] = make_int2(sup * N_NODES + src, __float_as_int(val));
}

// ---------------------------------------------------------------------------
// Gather: one wave per node, lane = channel, bf16 ps rows (128 B coalesced),
// 4-way load ILP, fused ReLU. Atomic-free.
// ---------------------------------------------------------------------------
__global__ __launch_bounds__(256) void gather_kernel(
    const ushort* __restrict__ psb, const int* __restrict__ start,
    const int2* __restrict__ erec, float* __restrict__ out)
{
    const int n = blockIdx.x * 4 + (threadIdx.x >> 6);
    const int lane = threadIdx.x & 63;
    const int s = start[n];
    const int e = start[n + 1];

    float acc = 0.f;
    for (int base = s; base < e; base += 64) {
        const int cnt = min(64, e - base);
        int2 r = make_int2(0, 0);
        if (base + lane < e) r = erec[base + lane];
        int j = 0;
        for (; j + 4 <= cnt; j += 4) {
            int   r0 = __shfl(r.x, j),     r1 = __shfl(r.x, j + 1);
            int   r2 = __shfl(r.x, j + 2), r3 = __shfl(r.x, j + 3);
            float v0 = __int_as_float(__shfl(r.y, j));
            float v1 = __int_as_float(__shfl(r.y, j + 1));
            float v2 = __int_as_float(__shfl(r.y, j + 2));
            float v3 = __int_as_float(__shfl(r.y, j + 3));
            float p0 = bf2f(psb[(size_t)r0 * OUT_DIM + lane]);
            float p1 = bf2f(psb[(size_t)r1 * OUT_DIM + lane]);
            float p2 = bf2f(psb[(size_t)r2 * OUT_DIM + lane]);
            float p3 = bf2f(psb[(size_t)r3 * OUT_DIM + lane]);
            acc = fmaf(p0, v0, acc);
            acc = fmaf(p1, v1, acc);
            acc = fmaf(p2, v2, acc);
            acc = fmaf(p3, v3, acc);
        }
        for (; j < cnt; ++j) {
            int   row = __shfl(r.x, j);
            float val = __int_as_float(__shfl(r.y, j));
            acc = fmaf(bf2f(psb[(size_t)row * OUT_DIM + lane]), val, acc);
        }
    }
    out[(size_t)n * OUT_DIM + lane] = fmaxf(acc, 0.f);
}

extern "C" void kernel_launch(void* const* d_in, const int* in_sizes, int n_in,
                              void* d_out, int out_size, void* d_ws, size_t ws_size,
                              hipStream_t stream)
{
    const float* x        = (const float*)d_in[0];
    const float* W        = (const float*)d_in[1];
    const float* edge_val = (const float*)d_in[2];
    const int*   edge_src = (const int*)d_in[3];
    const int*   edge_dst = (const int*)d_in[4];
    float* out = (float*)d_out;

    // workspace layout:
    //   psb    [2*100000*64 bf16]  @ 0          (25,600,000 B)
    //   deg    [N1 int]            @ 25,600,000 (pad 400,016)
    //   start  [N1 int]            @ 26,000,016
    //   cursor [N1 int]            @ 26,400,032
    //   erec   [3.2M int2]         @ 26,800,048 (25,600,000 B)
    //   bsum   [98 int]            @ 52,400,048
    //   Wb     [32768 ushort]      @ 52,400,448 (16B-aligned; 65,536 B)
    ushort* psb = (ushort*)d_ws;
    char* p = (char*)d_ws + 25600000;
    int*  deg    = (int*)(p);
    int*  start  = (int*)(p + 400016);
    int*  cursor = (int*)(p + 800032);
    int2* erec   = (int2*)(p + 1200048);
    int*  bsum   = (int*)(p + 26800048);
    ushort* Wb   = (ushort*)(p + 26800448);

    wb_kernel<<<128, 256, 0, stream>>>(W, Wb);
    gemm_kernel<<<NBLK, 256, 0, stream>>>(x, Wb, psb);

    zero_deg_kernel<<<(N1 + 255) / 256, 256, 0, stream>>>(deg);
    hist_kernel<<<N_TOT_EDGES / 256, 256, 0, stream>>>(edge_dst, deg);
    scan1_kernel<<<SCAN_NB, 256, 0, stream>>>(deg, bsum);
    scan2_kernel<<<1, 64, 0, stream>>>(bsum);
    scan3_kernel<<<SCAN_NB, 256, 0, stream>>>(deg, bsum, start, cursor);
    fill_kernel<<<N_TOT_EDGES / 256, 256, 0, stream>>>(edge_src, edge_dst,
                                                       edge_val, cursor, erec);

    gather_kernel<<<N_NODES / 4, 256, 0, stream>>>(psb, start, erec, out);
}

// Round 4
// 495.360 us; speedup vs baseline: 2.0096x; 1.3145x over previous
//
#include <hip/hip_runtime.h>

#define N_NODES 100000
#define N_EDGES 1600000
#define N_SUP 2
#define IN_DIM 256
#define OUT_DIM 64
#define N_TOT_EDGES (N_SUP * N_EDGES)   // 3,200,000
#define N1 (N_NODES + 1)                // scan length
#define GM 64                           // GEMM M-tile per block
#define NBLK ((N_NODES + GM - 1) / GM)  // 1563

#define SHIFT 10                        // 1024 nodes per bucket
#define NBUCK 98                        // ceil(100000 / 1024)
#define CHUNK 4096                      // edges per bin-phase block
#define BGRID ((N_TOT_EDGES + CHUNK - 1) / CHUNK)  // 782

typedef __attribute__((ext_vector_type(8))) short short8;   // 8 bf16
typedef __attribute__((ext_vector_type(4))) float floatx4;  // MFMA acc
typedef unsigned long long u64;

__device__ inline ushort f2bf(float f) {          // fp32 -> bf16 RNE
    unsigned u = __float_as_uint(f);
    return (ushort)((u + 0x7fffu + ((u >> 16) & 1u)) >> 16);
}
__device__ inline float bf2f(ushort h) {
    return __uint_as_float(((unsigned)h) << 16);
}

// ---------------------------------------------------------------------------
// W pre-swizzle into mfma_f32_16x16x32_bf16 B-fragment order (unchanged R3).
// ---------------------------------------------------------------------------
__global__ __launch_bounds__(256) void wb_kernel(
    const float* __restrict__ W, ushort* __restrict__ Wb)
{
    int idx = blockIdx.x * 256 + threadIdx.x;      // 0..32767
    int j    = idx & 7;
    int lane = (idx >> 3) & 63;
    int nt   = (idx >> 9) & 7;
    int ks   = idx >> 12;
    int k = ks * 32 + (lane >> 4) * 8 + j;
    int n = nt * 16 + (lane & 15);
    Wb[idx] = f2bf(W[((size_t)(n >> 6) * IN_DIM + k) * OUT_DIM + (n & 63)]);
}

// ---------------------------------------------------------------------------
// MFMA GEMM (unchanged R3): psb[sup][node][64] bf16 = x @ W[sup], C[100000x128]
// ---------------------------------------------------------------------------
__global__ __launch_bounds__(256) void gemm_kernel(
    const float* __restrict__ x, const ushort* __restrict__ Wb,
    ushort* __restrict__ psb)
{
    __shared__ __align__(16) ushort xs[GM][264];
    const int row0 = blockIdx.x * GM;
    const int trow = threadIdx.x >> 6;
    const int tcol = threadIdx.x & 63;

#pragma unroll
    for (int j = 0; j < 16; ++j) {
        int r = j * 4 + trow;
        int gr = row0 + r;
        if (gr > N_NODES - 1) gr = N_NODES - 1;
        float4 v = ((const float4*)x)[(size_t)gr * 64 + tcol];
        ushort4 h;
        h.x = f2bf(v.x); h.y = f2bf(v.y); h.z = f2bf(v.z); h.w = f2bf(v.w);
        *(ushort4*)&xs[r][tcol * 4] = h;
    }
    __syncthreads();

    const int wave = threadIdx.x >> 6;
    const int lane = threadIdx.x & 63;
    const int q = lane >> 4;
    const int m = lane & 15;
    const int nt0 = wave * 2;

    floatx4 acc[4][2];
#pragma unroll
    for (int mt = 0; mt < 4; ++mt)
#pragma unroll
        for (int nt = 0; nt < 2; ++nt)
            acc[mt][nt] = (floatx4){0.f, 0.f, 0.f, 0.f};

    const short8* Wbv = (const short8*)Wb;
#pragma unroll
    for (int ks = 0; ks < 8; ++ks) {
        short8 b0 = Wbv[((ks * 8) + nt0) * 64 + lane];
        short8 b1 = Wbv[((ks * 8) + nt0 + 1) * 64 + lane];
#pragma unroll
        for (int mt = 0; mt < 4; ++mt) {
            short8 a = *(const short8*)&xs[mt * 16 + m][ks * 32 + q * 8];
            acc[mt][0] = __builtin_amdgcn_mfma_f32_16x16x32_bf16(a, b0, acc[mt][0], 0, 0, 0);
            acc[mt][1] = __builtin_amdgcn_mfma_f32_16x16x32_bf16(a, b1, acc[mt][1], 0, 0, 0);
        }
    }

#pragma unroll
    for (int mt = 0; mt < 4; ++mt) {
#pragma unroll
        for (int nt = 0; nt < 2; ++nt) {
            int col = wave * 32 + nt * 16 + m;
            int sup = col >> 6, ch = col & 63;
#pragma unroll
            for (int r = 0; r < 4; ++r) {
                int row = row0 + mt * 16 + q * 4 + r;
                if (row < N_NODES)
                    psb[((size_t)sup * N_NODES + row) * OUT_DIM + ch] =
                        f2bf(acc[mt][nt][r]);
            }
        }
    }
}

// ---------------------------------------------------------------------------
// Node-degree histogram + exclusive scan -> start[] (unchanged R3)
// ---------------------------------------------------------------------------
__global__ __launch_bounds__(256) void zero_deg_kernel(int* __restrict__ deg)
{
    int i = blockIdx.x * 256 + threadIdx.x;
    if (i < N1) deg[i] = 0;
}

__global__ __launch_bounds__(256) void hist_kernel(
    const int* __restrict__ edge_dst, int* __restrict__ deg)
{
    int gid = blockIdx.x * 256 + threadIdx.x;
    atomicAdd(&deg[edge_dst[gid]], 1);
}

#define SCAN_NB ((N1 + 1023) / 1024)            // 98
__global__ __launch_bounds__(256) void scan1_kernel(
    const int* __restrict__ deg, int* __restrict__ bsum)
{
    __shared__ int sh[256];
    int base = blockIdx.x * 1024 + threadIdx.x * 4;
    int s = 0;
#pragma unroll
    for (int j = 0; j < 4; ++j) {
        int idx = base + j;
        if (idx < N1) s += deg[idx];
    }
    sh[threadIdx.x] = s;
    __syncthreads();
    for (int off = 128; off > 0; off >>= 1) {
        if (threadIdx.x < off) sh[threadIdx.x] += sh[threadIdx.x + off];
        __syncthreads();
    }
    if (threadIdx.x == 0) bsum[blockIdx.x] = sh[0];
}

__global__ void scan2_kernel(int* __restrict__ bsum)
{
    if (threadIdx.x == 0 && blockIdx.x == 0) {
        int acc = 0;
        for (int i = 0; i < SCAN_NB; ++i) {
            int v = bsum[i];
            bsum[i] = acc;
            acc += v;
        }
    }
}

__global__ __launch_bounds__(256) void scan3_kernel(
    const int* __restrict__ deg, const int* __restrict__ bsum,
    int* __restrict__ start)
{
    __shared__ int sh[256];
    int base = blockIdx.x * 1024 + threadIdx.x * 4;
    int v[4];
    int tsum = 0;
#pragma unroll
    for (int j = 0; j < 4; ++j) {
        int idx = base + j;
        v[j] = (idx < N1) ? deg[idx] : 0;
        tsum += v[j];
    }
    sh[threadIdx.x] = tsum;
    __syncthreads();
    for (int off = 1; off < 256; off <<= 1) {
        int add = (threadIdx.x >= off) ? sh[threadIdx.x - off] : 0;
        __syncthreads();
        sh[threadIdx.x] += add;
        __syncthreads();
    }
    int pre = sh[threadIdx.x] - tsum + bsum[blockIdx.x];
#pragma unroll
    for (int j = 0; j < 4; ++j) {
        int idx = base + j;
        if (idx < N1) start[idx] = pre;
        pre += v[j];
    }
}

// bucket cursors = CSR offsets at bucket boundaries
__global__ void binit_kernel(const int* __restrict__ start, int* __restrict__ bcur)
{
    int b = threadIdx.x;
    if (b < NBUCK) bcur[b] = start[b << SHIFT];
}

// ---------------------------------------------------------------------------
// Phase B: bin edges by bucket (dst>>10) into bucket-major staging sbuf.
// Per block: LDS hist over 98 buckets, ONE global atomic per touched bucket,
// then block-private contiguous chunk writes (~32 edges = 256 B per bucket)
// -> lines fill in this XCD's L2. Record packs (val:32|srcsup:18|dst_lo:10).
// ---------------------------------------------------------------------------
__global__ __launch_bounds__(256) void bin_kernel(
    const int* __restrict__ edge_src, const int* __restrict__ edge_dst,
    const float* __restrict__ edge_val,
    int* __restrict__ bcur, u64* __restrict__ sbuf)
{
    __shared__ int hist[NBUCK], gbase[NBUCK], cnt[NBUCK];
    const int base = blockIdx.x * CHUNK + threadIdx.x;

    u64 pk[16];
    int bk[16];
    if (threadIdx.x < NBUCK) hist[threadIdx.x] = 0;
    __syncthreads();

#pragma unroll
    for (int j = 0; j < 16; ++j) {
        int gid = base + j * 256;
        bk[j] = -1;
        if (gid < N_TOT_EDGES) {
            int dst = edge_dst[gid];
            int src = edge_src[gid];
            float val = edge_val[gid];
            int srcsup = (gid >= N_EDGES ? N_NODES : 0) + src;
            bk[j] = dst >> SHIFT;
            pk[j] = ((u64)__float_as_uint(val) << 32)
                  | (u64)(((unsigned)srcsup << 10) | (unsigned)(dst & 1023));
            atomicAdd(&hist[bk[j]], 1);
        }
    }
    __syncthreads();
    if (threadIdx.x < NBUCK) {
        int h = hist[threadIdx.x];
        gbase[threadIdx.x] = (h > 0) ? atomicAdd(&bcur[threadIdx.x], h) : 0;
        cnt[threadIdx.x] = 0;
    }
    __syncthreads();
#pragma unroll
    for (int j = 0; j < 16; ++j) {
        if (bk[j] >= 0) {
            int loc = atomicAdd(&cnt[bk[j]], 1);
            sbuf[(size_t)gbase[bk[j]] + loc] = pk[j];
        }
    }
}

// ---------------------------------------------------------------------------
// Phase C: one 1024-thread block per bucket. Per-node cursors in LDS (no
// global atomics). Reads staged bucket contiguously; scatters into the final
// CSR erec within this bucket's 262 KB region -- single-XCD, L2-merged.
// ---------------------------------------------------------------------------
__global__ __launch_bounds__(1024) void group_kernel(
    const u64* __restrict__ sbuf, const int* __restrict__ start,
    int2* __restrict__ erec)
{
    __shared__ int cur[1024];
    const int b = blockIdx.x;
    const int n0 = b << SHIFT;
    {
        int n = n0 + threadIdx.x;
        cur[threadIdx.x] = (n < N_NODES) ? start[n] : 0;
    }
    __syncthreads();
    const int s = start[n0];
    const int e = start[min(n0 + 1024, N_NODES)];
    for (int i = s + (int)threadIdx.x; i < e; i += 1024) {
        u64 p = sbuf[i];
        int dl = (int)(p & 1023u);
        int srcsup = (int)((p >> 10) & 0x3FFFFu);
        int vb = (int)(p >> 32);
        int pos = atomicAdd(&cur[dl], 1);
        erec[pos] = make_int2(srcsup, vb);
    }
}

// ---------------------------------------------------------------------------
// Gather: one wave per node, lane = channel, bf16 ps rows, 4-way load ILP,
// fused ReLU. Atomic-free. (unchanged R3)
// ---------------------------------------------------------------------------
__global__ __launch_bounds__(256) void gather_kernel(
    const ushort* __restrict__ psb, const int* __restrict__ start,
    const int2* __restrict__ erec, float* __restrict__ out)
{
    const int n = blockIdx.x * 4 + (threadIdx.x >> 6);
    const int lane = threadIdx.x & 63;
    const int s = start[n];
    const int e = start[n + 1];

    float acc = 0.f;
    for (int base = s; base < e; base += 64) {
        const int cnt = min(64, e - base);
        int2 r = make_int2(0, 0);
        if (base + lane < e) r = erec[base + lane];
        int j = 0;
        for (; j + 4 <= cnt; j += 4) {
            int   r0 = __shfl(r.x, j),     r1 = __shfl(r.x, j + 1);
            int   r2 = __shfl(r.x, j + 2), r3 = __shfl(r.x, j + 3);
            float v0 = __int_as_float(__shfl(r.y, j));
            float v1 = __int_as_float(__shfl(r.y, j + 1));
            float v2 = __int_as_float(__shfl(r.y, j + 2));
            float v3 = __int_as_float(__shfl(r.y, j + 3));
            float p0 = bf2f(psb[(size_t)r0 * OUT_DIM + lane]);
            float p1 = bf2f(psb[(size_t)r1 * OUT_DIM + lane]);
            float p2 = bf2f(psb[(size_t)r2 * OUT_DIM + lane]);
            float p3 = bf2f(psb[(size_t)r3 * OUT_DIM + lane]);
            acc = fmaf(p0, v0, acc);
            acc = fmaf(p1, v1, acc);
            acc = fmaf(p2, v2, acc);
            acc = fmaf(p3, v3, acc);
        }
        for (; j < cnt; ++j) {
            int   row = __shfl(r.x, j);
            float val = __int_as_float(__shfl(r.y, j));
            acc = fmaf(bf2f(psb[(size_t)row * OUT_DIM + lane]), val, acc);
        }
    }
    out[(size_t)n * OUT_DIM + lane] = fmaxf(acc, 0.f);
}

extern "C" void kernel_launch(void* const* d_in, const int* in_sizes, int n_in,
                              void* d_out, int out_size, void* d_ws, size_t ws_size,
                              hipStream_t stream)
{
    const float* x        = (const float*)d_in[0];
    const float* W        = (const float*)d_in[1];
    const float* edge_val = (const float*)d_in[2];
    const int*   edge_src = (const int*)d_in[3];
    const int*   edge_dst = (const int*)d_in[4];
    float* out = (float*)d_out;

    // workspace layout (total 77,666,368 B <= R2's proven 78.0 MB footprint):
    //   psb   [2*100000*64 bf16] @ 0           (25,600,000)
    //   deg   [N1 int]           @ 25,600,000  (pad 400,016)
    //   start [N1 int]           @ 26,000,016  (pad 400,016)
    //   sbuf  [3.2M u64]         @ 26,400,032  (25,600,000)
    //   erec  [3.2M int2]        @ 52,000,032  (25,600,000)
    //   bcur  [98 int]           @ 77,600,032  (400)
    //   bsum  [98 int]           @ 77,600,432  (400)
    //   Wb    [32768 ushort]     @ 77,600,832  (65,536)
    ushort* psb = (ushort*)d_ws;
    char* p = (char*)d_ws;
    int*  deg    = (int*)(p + 25600000);
    int*  start  = (int*)(p + 26000016);
    u64*  sbuf   = (u64*)(p + 26400032);
    int2* erec   = (int2*)(p + 52000032);
    int*  bcur   = (int*)(p + 77600032);
    int*  bsum   = (int*)(p + 77600432);
    ushort* Wb   = (ushort*)(p + 77600832);

    wb_kernel<<<128, 256, 0, stream>>>(W, Wb);
    gemm_kernel<<<NBLK, 256, 0, stream>>>(x, Wb, psb);

    zero_deg_kernel<<<(N1 + 255) / 256, 256, 0, stream>>>(deg);
    hist_kernel<<<N_TOT_EDGES / 256, 256, 0, stream>>>(edge_dst, deg);
    scan1_kernel<<<SCAN_NB, 256, 0, stream>>>(deg, bsum);
    scan2_kernel<<<1, 64, 0, stream>>>(bsum);
    scan3_kernel<<<SCAN_NB, 256, 0, stream>>>(deg, bsum, start);
    binit_kernel<<<1, 128, 0, stream>>>(start, bcur);

    bin_kernel<<<BGRID, 256, 0, stream>>>(edge_src, edge_dst, edge_val,
                                          bcur, sbuf);
    group_kernel<<<NBUCK, 1024, 0, stream>>>(sbuf, start, erec);

    gather_kernel<<<N_NODES / 4, 256, 0, stream>>>(psb, start, erec, out);
}